// Round 17
// baseline (264.472 us; speedup 1.0000x reference)
//
#include <hip/hip_runtime.h>
#include <cstdint>
#include <cstddef>

#define EPSV 1e-5f

using f32x4  = __attribute__((ext_vector_type(4))) float;
using bf16x8 = __attribute__((ext_vector_type(8))) short;

// RNE pack of two f32 into two bf16 (lo -> low16, hi -> high16)
static __device__ __forceinline__ unsigned pk2(float lo, float hi) {
    unsigned a = __builtin_bit_cast(unsigned, lo);
    unsigned b = __builtin_bit_cast(unsigned, hi);
    a = (a + 0x7FFFu + ((a >> 16) & 1u)) >> 16;
    b = (b + 0x7FFFu + ((b >> 16) & 1u)) & 0xFFFF0000u;
    return a | b;
}
static __device__ __forceinline__ unsigned short bf16of(float v) {
    return (unsigned short)(pk2(v, 0.f) & 0xFFFFu);
}
static __device__ __forceinline__ void unpk2(unsigned u, float& lo, float& hi) {
    lo = __builtin_bit_cast(float, u << 16);
    hi = __builtin_bit_cast(float, u & 0xFFFF0000u);
}

// ---------------------------------------------------------------------------
__global__ __launch_bounds__(256) void prep_params(
    const float* __restrict__ rwb, const float* __restrict__ rg,
    const float* __restrict__ rb,  const float* __restrict__ rm,
    const float* __restrict__ rv,
    const float* __restrict__ ewb, const float* __restrict__ eg,
    const float* __restrict__ eb,  const float* __restrict__ em,
    const float* __restrict__ ev,
    const float* __restrict__ bg,  const float* __restrict__ bb,
    const float* __restrict__ bm,  const float* __restrict__ bv,
    float* __restrict__ prm)
{
    int t = threadIdx.x;
    if (t < 128) {
        float sc = rg[t] * rsqrtf(rv[t] + EPSV);
        prm[t]       = sc;
        prm[128 + t] = rb[t] - rm[t] * sc + rwb[t] * sc;
        float bsc = bg[t] * rsqrtf(bv[t] + EPSV);
        prm[768 + t] = bsc;
        prm[896 + t] = bb[t] - bm[t] * bsc;
    }
    {
        float sc = eg[t] * rsqrtf(ev[t] + EPSV);
        prm[256 + t] = sc;
        prm[512 + t] = eb[t] - em[t] * sc + ewb[t] * sc;
    }
}

// ---------------------------------------------------------------------------
// GEMM v2 (round-9/10 verified, unchanged): BK=64, 32 KB LDS, vectorized I/O.
// ---------------------------------------------------------------------------
template<int BMODE, int OUTMODE>
__global__ __launch_bounds__(256) void gemm_v2(
    const void* __restrict__ Bsrc,
    const float* __restrict__ Wt,
    const float* __restrict__ scale,
    const float* __restrict__ shift,
    const float* __restrict__ resid,
    void* __restrict__ OutP,
    int Cin, int O, int P)
{
    const int n    = blockIdx.z;
    const int p0   = blockIdx.x * 64;
    const int o0   = blockIdx.y * 128;
    const int tid  = threadIdx.x;
    const int lane = tid & 63;
    const int wid  = tid >> 6;
    const int wm   = wid >> 1, wn = wid & 1;
    const int rl   = lane & 15;

    __shared__ __align__(16) char smem[32768];
    short* sA = (short*)smem;                       // 16 KB [128][64] swz

    f32x4 acc[4][2];
    #pragma unroll
    for (int i = 0; i < 4; ++i)
        #pragma unroll
        for (int j = 0; j < 2; ++j) acc[i][j] = (f32x4)0.f;

    for (int kc = 0; kc < Cin; kc += 64) {
        if (kc) __syncthreads();

        #pragma unroll
        for (int it = 0; it < 4; ++it) {
            int idx = tid + it * 256;
            int row = idx >> 3, k8 = (idx & 7) << 3;
            const float* wp = Wt + (size_t)(o0 + row) * Cin + kc + k8;
            float4 u = *(const float4*)wp;
            float4 v = *(const float4*)(wp + 4);
            uint4 w = make_uint4(pk2(u.x, u.y), pk2(u.z, u.w),
                                 pk2(v.x, v.y), pk2(v.z, v.w));
            *(uint4*)(&sA[(row << 6) + (k8 ^ ((row & 7) << 3))]) = w;
        }
        if constexpr (BMODE == 0) {
            float* sBf = (float*)(smem + 16384);    // [64 k][64 p] rotated
            #pragma unroll
            for (int it = 0; it < 4; ++it) {
                int idx = tid + it * 256;
                int k = idx >> 4, p4 = (idx & 15) << 2;
                float4 u = *(const float4*)((const float*)Bsrc
                    + (size_t)n * Cin * P + (size_t)(kc + k) * P + p0 + p4);
                *(float4*)(&sBf[(k << 6) + ((p4 + (((k >> 3) & 7) << 3)) & 63)]) = u;
            }
        } else {
            short* sB = (short*)(smem + 16384);     // [64 p][64 k] swz
            #pragma unroll
            for (int it = 0; it < 2; ++it) {
                int idx = tid + it * 256;
                int p = idx >> 3, k8 = (idx & 7) << 3;
                uint4 w = *(const uint4*)((const unsigned short*)Bsrc
                    + ((size_t)n * P + p0 + p) * Cin + kc + k8);
                *(uint4*)(&sB[(p << 6) + (k8 ^ ((p & 7) << 3))]) = w;
            }
        }
        __syncthreads();

        #pragma unroll
        for (int ks = 0; ks < 2; ++ks) {
            const int k0 = ks * 32 + (lane >> 4) * 8;
            bf16x8 af[4], bfr[2];
            #pragma unroll
            for (int i = 0; i < 4; ++i) {
                int row = wm * 64 + i * 16 + rl;
                af[i] = *(const bf16x8*)(&sA[(row << 6) + (k0 ^ ((rl & 7) << 3))]);
            }
            if constexpr (BMODE == 0) {
                const float* sBf = (const float*)(smem + 16384);
                #pragma unroll
                for (int j = 0; j < 2; ++j) {
                    int p = wn * 32 + j * 16 + rl;
                    int base = (p + ((k0 >> 3) << 3)) & 63;
                    float f[8];
                    #pragma unroll
                    for (int q = 0; q < 8; ++q)
                        f[q] = sBf[((k0 + q) << 6) + base];
                    uint4 u = make_uint4(pk2(f[0], f[1]), pk2(f[2], f[3]),
                                         pk2(f[4], f[5]), pk2(f[6], f[7]));
                    bfr[j] = __builtin_bit_cast(bf16x8, u);
                }
            } else {
                const short* sB = (const short*)(smem + 16384);
                #pragma unroll
                for (int j = 0; j < 2; ++j) {
                    int p = wn * 32 + j * 16 + rl;
                    bfr[j] = *(const bf16x8*)(&sB[(p << 6) + (k0 ^ ((p & 7) << 3))]);
                }
            }
            #pragma unroll
            for (int i = 0; i < 4; ++i)
                #pragma unroll
                for (int j = 0; j < 2; ++j)
                    acc[i][j] = __builtin_amdgcn_mfma_f32_16x16x32_bf16(
                        af[i], bfr[j], acc[i][j], 0, 0, 0);
        }
    }

    if constexpr (OUTMODE == 1) {
        __syncthreads();
        unsigned short* eL = (unsigned short*)smem;   // [64 p][128 o]
        #pragma unroll
        for (int i = 0; i < 4; ++i) {
            #pragma unroll
            for (int r = 0; r < 4; ++r) {
                int ol = wm * 64 + i * 16 + (lane >> 4) * 4 + r;
                int o  = o0 + ol;
                float sc = scale[o], sh = shift[o];
                #pragma unroll
                for (int j = 0; j < 2; ++j) {
                    int p = wn * 32 + j * 16 + rl;
                    float v = fmaxf(fmaf(acc[i][j][r], sc, sh), 0.f);
                    eL[p * 128 + (ol ^ ((p & 15) << 3))] = bf16of(v);
                }
            }
        }
        __syncthreads();
        unsigned short* out = (unsigned short*)OutP;
        #pragma unroll
        for (int it = 0; it < 4; ++it) {
            int idx = tid + it * 256;
            int p = idx >> 4, m = idx & 15;
            uint4 u = *(const uint4*)(&eL[p * 128 + ((m ^ (p & 15)) << 3)]);
            *(uint4*)(out + ((size_t)n * P + p0 + p) * O + (m << 3)) = u;
        }
    } else {
        __syncthreads();
        float* eT = (float*)smem;                     // [128 o][64 p] rotated
        #pragma unroll
        for (int i = 0; i < 4; ++i) {
            #pragma unroll
            for (int r = 0; r < 4; ++r) {
                int ol = wm * 64 + i * 16 + (lane >> 4) * 4 + r;
                int o  = o0 + ol;
                float sc = scale[o], sh = shift[o];
                #pragma unroll
                for (int j = 0; j < 2; ++j) {
                    int p = wn * 32 + j * 16 + rl;
                    eT[(ol << 6) + ((p + ((ol & 7) << 3)) & 63)] =
                        fmaf(acc[i][j][r], sc, sh);
                }
            }
        }
        __syncthreads();
        float* out = (float*)OutP;
        #pragma unroll
        for (int it = 0; it < 8; ++it) {
            int idx = tid + it * 256;
            int ol = idx >> 4, p4 = (idx & 15) << 2;
            float4 v = *(const float4*)(&eT[(ol << 6) + ((p4 + ((ol & 7) << 3)) & 63)]);
            size_t base = ((size_t)n * O + o0 + ol) * P + p0 + p4;
            if (resid) {
                float4 r4 = *(const float4*)(resid + base);
                v.x += r4.x; v.y += r4.y; v.z += r4.z; v.w += r4.w;
            }
            v.x = fmaxf(v.x, 0.f); v.y = fmaxf(v.y, 0.f);
            v.z = fmaxf(v.z, 0.f); v.w = fmaxf(v.w, 0.f);
            *(float4*)(out + base) = v;
        }
    }
}

// ---------------------------------------------------------------------------
// Fused res2net chain (round-10 structure, f32 LDS state). Conv inner loop
// vectorized: sp reads as 2x float4 per (v, kb-block of 8 cin); weights for
// one kb-block held in registers (kb loop NOT unrolled to bound pressure).
// ---------------------------------------------------------------------------
__global__ __launch_bounds__(256) void gcn_fused(
    const unsigned short* __restrict__ hT,
    unsigned short* __restrict__ outsT,
    const float* __restrict__ gw,
    const float* __restrict__ gb,
    const float* __restrict__ Aadj,
    const float* __restrict__ PA,
    const float* __restrict__ bsc4,
    const float* __restrict__ bsh4)
{
    const int n  = blockIdx.y;
    const int tt = blockIdx.x;
    const int tid = threadIdx.x;
    const int c  = tid & 31;
    const int tl = tid >> 5;

    __shared__ float sp[200 * 36];              // 28.8 KB, f32 state
    __shared__ float wsg[96 * 33];              // 12.7 KB
    __shared__ float Mm[3][25][28];             //  8.4 KB
    __shared__ unsigned short outb[200 * 32];   // 12.8 KB

    const size_t rowbase = (size_t)n * 1600 + (size_t)tt * 200;

    // ---- init: sp = h chunk 0 (f32), stage step-0 weights ----
    {
        const unsigned short* hrow = hT + rowbase * 128;
        for (int idx = tid; idx < 800; idx += 256) {
            int p = idx >> 2, c8 = (idx & 3) << 3;
            uint4 u = *(const uint4*)(hrow + (size_t)p * 128 + c8);
            float f[8];
            unpk2(u.x, f[0], f[1]); unpk2(u.y, f[2], f[3]);
            unpk2(u.z, f[4], f[5]); unpk2(u.w, f[6], f[7]);
            float* d = sp + p * 36 + c8;
            *(float4*)d       = make_float4(f[0], f[1], f[2], f[3]);
            *(float4*)(d + 4) = make_float4(f[4], f[5], f[6], f[7]);
        }
        for (int idx = tid; idx < 96 * 32; idx += 256)
            wsg[(idx >> 5) * 33 + (idx & 31)] = gw[idx];
        for (int idx = tid; idx < 1875; idx += 256) {
            int k = idx / 625, rem = idx % 625;
            Mm[k][rem / 25][rem % 25] = Aadj[idx] + PA[idx];
        }
    }
    __syncthreads();

    for (int step = 0; step < 4; ++step) {
        // ---- conv 32->96: vectorized sp reads, kb-blocked weights ----
        float g[3][25];
        {
            const float* gbp = gb + step * 96;
            float b0 = gbp[c], b1 = gbp[32 + c], b2 = gbp[64 + c];
            #pragma unroll
            for (int v = 0; v < 25; ++v) { g[0][v] = b0; g[1][v] = b1; g[2][v] = b2; }
        }
        const float* srow = sp + tl * 25 * 36;
        #pragma unroll 1
        for (int kb = 0; kb < 32; kb += 8) {
            float w0[8], w1[8], w2[8];
            #pragma unroll
            for (int q = 0; q < 8; ++q) {
                w0[q] = wsg[c * 33 + kb + q];
                w1[q] = wsg[(32 + c) * 33 + kb + q];
                w2[q] = wsg[(64 + c) * 33 + kb + q];
            }
            #pragma unroll
            for (int v = 0; v < 25; ++v) {
                float4 fa = *(const float4*)(srow + v * 36 + kb);
                float4 fb = *(const float4*)(srow + v * 36 + kb + 4);
                float f[8] = {fa.x, fa.y, fa.z, fa.w, fb.x, fb.y, fb.z, fb.w};
                #pragma unroll
                for (int q = 0; q < 8; ++q) {
                    g[0][v] = fmaf(w0[q], f[q], g[0][v]);
                    g[1][v] = fmaf(w1[q], f[q], g[1][v]);
                    g[2][v] = fmaf(w2[q], f[q], g[2][v]);
                }
            }
        }

        // ---- adjacency mix ----
        float out[25];
        #pragma unroll
        for (int w = 0; w < 25; ++w) out[w] = 0.f;
        #pragma unroll
        for (int k = 0; k < 3; ++k)
            #pragma unroll
            for (int v = 0; v < 25; ++v) {
                float gv = g[k][v];
                #pragma unroll
                for (int w = 0; w < 25; ++w)
                    out[w] = fmaf(gv, Mm[k][v][w], out[w]);
            }

        // ---- BN + ReLU ----
        {
            float sc = bsc4[step * 32 + c], sh = bsh4[step * 32 + c];
            #pragma unroll
            for (int w = 0; w < 25; ++w)
                out[w] = fmaxf(fmaf(out[w], sc, sh), 0.f);
        }

        __syncthreads();   // all conv/mix reads of sp, wsg, Mm complete

        // ---- write new sp (f32, next step's input) + bf16 outb ----
        #pragma unroll
        for (int w = 0; w < 25; ++w) {
            sp[(tl * 25 + w) * 36 + c] = out[w];
            outb[(tl * 25 + w) * 32 + c] = bf16of(out[w]);
        }
        __syncthreads();   // sp/outb writes complete

        // ---- store outb -> outsT chunk `step` (coalesced uint4) ----
        {
            unsigned short* orow = outsT + rowbase * 128 + step * 32;
            for (int idx = tid; idx < 800; idx += 256) {
                int p = idx >> 2, c8 = (idx & 3) << 3;
                uint4 u = *(const uint4*)(&outb[p * 32 + c8]);
                *(uint4*)(orow + (size_t)p * 128 + c8) = u;
            }
        }

        if (step < 3) {
            // ---- sp += h chunk step+1 ; stage next weights ----
            const unsigned short* hrow = hT + rowbase * 128 + (step + 1) * 32;
            for (int idx = tid; idx < 800; idx += 256) {
                int p = idx >> 2, c8 = (idx & 3) << 3;
                uint4 u = *(const uint4*)(hrow + (size_t)p * 128 + c8);
                float f[8];
                unpk2(u.x, f[0], f[1]); unpk2(u.y, f[2], f[3]);
                unpk2(u.z, f[4], f[5]); unpk2(u.w, f[6], f[7]);
                float* d = sp + p * 36 + c8;
                #pragma unroll
                for (int q = 0; q < 8; ++q) d[q] += f[q];
            }
            const float* gwp = gw + (step + 1) * 96 * 32;
            for (int idx = tid; idx < 96 * 32; idx += 256)
                wsg[(idx >> 5) * 33 + (idx & 31)] = gwp[idx];
            const float* pap = PA + (step + 1) * 1875;
            for (int idx = tid; idx < 1875; idx += 256) {
                int k = idx / 625, rem = idx % 625;
                Mm[k][rem / 25][rem % 25] = Aadj[idx] + pap[idx];
            }
            __syncthreads();   // sp/wsg/Mm ready for next conv
        }
    }
}

// ---------------------------------------------------------------------------
extern "C" void kernel_launch(void* const* d_in, const int* in_sizes, int n_in,
                              void* d_out, int out_size, void* d_ws, size_t ws_size,
                              hipStream_t stream)
{
    const float* x   = (const float*)d_in[0];
    const float* A   = (const float*)d_in[1];
    const float* rw  = (const float*)d_in[2];
    const float* rwb = (const float*)d_in[3];
    const float* rg  = (const float*)d_in[4];
    const float* rb  = (const float*)d_in[5];
    const float* rm  = (const float*)d_in[6];
    const float* rv  = (const float*)d_in[7];
    const float* gw  = (const float*)d_in[8];
    const float* gb  = (const float*)d_in[9];
    const float* PA  = (const float*)d_in[10];
    const float* bg  = (const float*)d_in[11];
    const float* bb  = (const float*)d_in[12];
    const float* bm  = (const float*)d_in[13];
    const float* bv  = (const float*)d_in[14];
    const float* ew  = (const float*)d_in[15];
    const float* ewb = (const float*)d_in[16];
    const float* eg  = (const float*)d_in[17];
    const float* eb  = (const float*)d_in[18];
    const float* em  = (const float*)d_in[19];
    const float* ev  = (const float*)d_in[20];

    char* wsb = (char*)d_ws;
    unsigned short* hT    = (unsigned short*)wsb;               // 26,214,400 B
    unsigned short* outsT = (unsigned short*)(wsb + 26214400);  // 26,214,400 B
    float*          prm   = (float*)(wsb + 52428800);           // 4 KB

    prep_params<<<1, 256, 0, stream>>>(rwb, rg, rb, rm, rv,
                                       ewb, eg, eb, em, ev,
                                       bg, bb, bm, bv, prm);

    // reduct: x f32 [n][256][1600] -> hT bf16 [n][1600][128]
    gemm_v2<0, 1><<<dim3(25, 1, 64), 256, 0, stream>>>(
        x, rw, prm, prm + 128, nullptr, hT, 256, 128, 1600);

    // fused res2net chain (4 steps, one launch)
    gcn_fused<<<dim3(8, 64), 256, 0, stream>>>(
        hT, outsT, gw, gb, A, PA, prm + 768, prm + 896);

    // expand: outsT bf16 -> d_out f32 [n][256][1600] (+x residual)
    gemm_v2<1, 0><<<dim3(25, 2, 64), 256, 0, stream>>>(
        outsT, ew, prm + 256, prm + 512, x, d_out, 128, 256, 1600);
}

// Round 18
// 189.864 us; speedup vs baseline: 1.3930x; 1.3930x over previous
//
#include <hip/hip_runtime.h>
#include <cstdint>
#include <cstddef>

#define EPSV 1e-5f

using f32x4  = __attribute__((ext_vector_type(4))) float;
using bf16x8 = __attribute__((ext_vector_type(8))) short;

// RNE pack of two f32 into two bf16 (lo -> low16, hi -> high16)
static __device__ __forceinline__ unsigned pk2(float lo, float hi) {
    unsigned a = __builtin_bit_cast(unsigned, lo);
    unsigned b = __builtin_bit_cast(unsigned, hi);
    a = (a + 0x7FFFu + ((a >> 16) & 1u)) >> 16;
    b = (b + 0x7FFFu + ((b >> 16) & 1u)) & 0xFFFF0000u;
    return a | b;
}
static __device__ __forceinline__ unsigned short bf16of(float v) {
    return (unsigned short)(pk2(v, 0.f) & 0xFFFFu);
}
static __device__ __forceinline__ void unpk2(unsigned u, float& lo, float& hi) {
    lo = __builtin_bit_cast(float, u << 16);
    hi = __builtin_bit_cast(float, u & 0xFFFF0000u);
}

// ---------------------------------------------------------------------------
__global__ __launch_bounds__(256) void prep_params(
    const float* __restrict__ rwb, const float* __restrict__ rg,
    const float* __restrict__ rb,  const float* __restrict__ rm,
    const float* __restrict__ rv,
    const float* __restrict__ ewb, const float* __restrict__ eg,
    const float* __restrict__ eb,  const float* __restrict__ em,
    const float* __restrict__ ev,
    const float* __restrict__ bg,  const float* __restrict__ bb,
    const float* __restrict__ bm,  const float* __restrict__ bv,
    float* __restrict__ prm)
{
    int t = threadIdx.x;
    if (t < 128) {
        float sc = rg[t] * rsqrtf(rv[t] + EPSV);
        prm[t]       = sc;
        prm[128 + t] = rb[t] - rm[t] * sc + rwb[t] * sc;
        float bsc = bg[t] * rsqrtf(bv[t] + EPSV);
        prm[768 + t] = bsc;
        prm[896 + t] = bb[t] - bm[t] * bsc;
    }
    {
        float sc = eg[t] * rsqrtf(ev[t] + EPSV);
        prm[256 + t] = sc;
        prm[512 + t] = eb[t] - em[t] * sc + ewb[t] * sc;
    }
}

// ---------------------------------------------------------------------------
// GEMM v2 (round-9/10 verified, unchanged): BK=64, 32 KB LDS, vectorized I/O.
// ---------------------------------------------------------------------------
template<int BMODE, int OUTMODE>
__global__ __launch_bounds__(256) void gemm_v2(
    const void* __restrict__ Bsrc,
    const float* __restrict__ Wt,
    const float* __restrict__ scale,
    const float* __restrict__ shift,
    const float* __restrict__ resid,
    void* __restrict__ OutP,
    int Cin, int O, int P)
{
    const int n    = blockIdx.z;
    const int p0   = blockIdx.x * 64;
    const int o0   = blockIdx.y * 128;
    const int tid  = threadIdx.x;
    const int lane = tid & 63;
    const int wid  = tid >> 6;
    const int wm   = wid >> 1, wn = wid & 1;
    const int rl   = lane & 15;

    __shared__ __align__(16) char smem[32768];
    short* sA = (short*)smem;                       // 16 KB [128][64] swz

    f32x4 acc[4][2];
    #pragma unroll
    for (int i = 0; i < 4; ++i)
        #pragma unroll
        for (int j = 0; j < 2; ++j) acc[i][j] = (f32x4)0.f;

    for (int kc = 0; kc < Cin; kc += 64) {
        if (kc) __syncthreads();

        #pragma unroll
        for (int it = 0; it < 4; ++it) {
            int idx = tid + it * 256;
            int row = idx >> 3, k8 = (idx & 7) << 3;
            const float* wp = Wt + (size_t)(o0 + row) * Cin + kc + k8;
            float4 u = *(const float4*)wp;
            float4 v = *(const float4*)(wp + 4);
            uint4 w = make_uint4(pk2(u.x, u.y), pk2(u.z, u.w),
                                 pk2(v.x, v.y), pk2(v.z, v.w));
            *(uint4*)(&sA[(row << 6) + (k8 ^ ((row & 7) << 3))]) = w;
        }
        if constexpr (BMODE == 0) {
            float* sBf = (float*)(smem + 16384);    // [64 k][64 p] rotated
            #pragma unroll
            for (int it = 0; it < 4; ++it) {
                int idx = tid + it * 256;
                int k = idx >> 4, p4 = (idx & 15) << 2;
                float4 u = *(const float4*)((const float*)Bsrc
                    + (size_t)n * Cin * P + (size_t)(kc + k) * P + p0 + p4);
                *(float4*)(&sBf[(k << 6) + ((p4 + (((k >> 3) & 7) << 3)) & 63)]) = u;
            }
        } else {
            short* sB = (short*)(smem + 16384);     // [64 p][64 k] swz
            #pragma unroll
            for (int it = 0; it < 2; ++it) {
                int idx = tid + it * 256;
                int p = idx >> 3, k8 = (idx & 7) << 3;
                uint4 w = *(const uint4*)((const unsigned short*)Bsrc
                    + ((size_t)n * P + p0 + p) * Cin + kc + k8);
                *(uint4*)(&sB[(p << 6) + (k8 ^ ((p & 7) << 3))]) = w;
            }
        }
        __syncthreads();

        #pragma unroll
        for (int ks = 0; ks < 2; ++ks) {
            const int k0 = ks * 32 + (lane >> 4) * 8;
            bf16x8 af[4], bfr[2];
            #pragma unroll
            for (int i = 0; i < 4; ++i) {
                int row = wm * 64 + i * 16 + rl;
                af[i] = *(const bf16x8*)(&sA[(row << 6) + (k0 ^ ((rl & 7) << 3))]);
            }
            if constexpr (BMODE == 0) {
                const float* sBf = (const float*)(smem + 16384);
                #pragma unroll
                for (int j = 0; j < 2; ++j) {
                    int p = wn * 32 + j * 16 + rl;
                    int base = (p + ((k0 >> 3) << 3)) & 63;
                    float f[8];
                    #pragma unroll
                    for (int q = 0; q < 8; ++q)
                        f[q] = sBf[((k0 + q) << 6) + base];
                    uint4 u = make_uint4(pk2(f[0], f[1]), pk2(f[2], f[3]),
                                         pk2(f[4], f[5]), pk2(f[6], f[7]));
                    bfr[j] = __builtin_bit_cast(bf16x8, u);
                }
            } else {
                const short* sB = (const short*)(smem + 16384);
                #pragma unroll
                for (int j = 0; j < 2; ++j) {
                    int p = wn * 32 + j * 16 + rl;
                    bfr[j] = *(const bf16x8*)(&sB[(p << 6) + (k0 ^ ((p & 7) << 3))]);
                }
            }
            #pragma unroll
            for (int i = 0; i < 4; ++i)
                #pragma unroll
                for (int j = 0; j < 2; ++j)
                    acc[i][j] = __builtin_amdgcn_mfma_f32_16x16x32_bf16(
                        af[i], bfr[j], acc[i][j], 0, 0, 0);
        }
    }

    if constexpr (OUTMODE == 1) {
        __syncthreads();
        unsigned short* eL = (unsigned short*)smem;   // [64 p][128 o]
        #pragma unroll
        for (int i = 0; i < 4; ++i) {
            #pragma unroll
            for (int r = 0; r < 4; ++r) {
                int ol = wm * 64 + i * 16 + (lane >> 4) * 4 + r;
                int o  = o0 + ol;
                float sc = scale[o], sh = shift[o];
                #pragma unroll
                for (int j = 0; j < 2; ++j) {
                    int p = wn * 32 + j * 16 + rl;
                    float v = fmaxf(fmaf(acc[i][j][r], sc, sh), 0.f);
                    eL[p * 128 + (ol ^ ((p & 15) << 3))] = bf16of(v);
                }
            }
        }
        __syncthreads();
        unsigned short* out = (unsigned short*)OutP;
        #pragma unroll
        for (int it = 0; it < 4; ++it) {
            int idx = tid + it * 256;
            int p = idx >> 4, m = idx & 15;
            uint4 u = *(const uint4*)(&eL[p * 128 + ((m ^ (p & 15)) << 3)]);
            *(uint4*)(out + ((size_t)n * P + p0 + p) * O + (m << 3)) = u;
        }
    } else {
        __syncthreads();
        float* eT = (float*)smem;                     // [128 o][64 p] rotated
        #pragma unroll
        for (int i = 0; i < 4; ++i) {
            #pragma unroll
            for (int r = 0; r < 4; ++r) {
                int ol = wm * 64 + i * 16 + (lane >> 4) * 4 + r;
                int o  = o0 + ol;
                float sc = scale[o], sh = shift[o];
                #pragma unroll
                for (int j = 0; j < 2; ++j) {
                    int p = wn * 32 + j * 16 + rl;
                    eT[(ol << 6) + ((p + ((ol & 7) << 3)) & 63)] =
                        fmaf(acc[i][j][r], sc, sh);
                }
            }
        }
        __syncthreads();
        float* out = (float*)OutP;
        #pragma unroll
        for (int it = 0; it < 8; ++it) {
            int idx = tid + it * 256;
            int ol = idx >> 4, p4 = (idx & 15) << 2;
            float4 v = *(const float4*)(&eT[(ol << 6) + ((p4 + ((ol & 7) << 3)) & 63)]);
            size_t base = ((size_t)n * O + o0 + ol) * P + p0 + p4;
            if (resid) {
                float4 r4 = *(const float4*)(resid + base);
                v.x += r4.x; v.y += r4.y; v.z += r4.z; v.w += r4.w;
            }
            v.x = fmaxf(v.x, 0.f); v.y = fmaxf(v.y, 0.f);
            v.z = fmaxf(v.z, 0.f); v.w = fmaxf(v.w, 0.f);
            *(float4*)(out + base) = v;
        }
    }
}

// ---------------------------------------------------------------------------
// Fused res2net chain: round-10 structure verbatim EXCEPT the adjacency mix
// reads Mm rows as float4 (6 x ds_read_b128 + 1 x b32 per (k,v) instead of
// 25 x b32). Conv loop untouched (116-VGPR verified form).
// ---------------------------------------------------------------------------
__global__ __launch_bounds__(256) void gcn_fused(
    const unsigned short* __restrict__ hT,
    unsigned short* __restrict__ outsT,
    const float* __restrict__ gw,
    const float* __restrict__ gb,
    const float* __restrict__ Aadj,
    const float* __restrict__ PA,
    const float* __restrict__ bsc4,
    const float* __restrict__ bsh4)
{
    const int n  = blockIdx.y;
    const int tt = blockIdx.x;
    const int tid = threadIdx.x;
    const int c  = tid & 31;
    const int tl = tid >> 5;

    __shared__ float sp[200 * 36];              // 28.8 KB, f32 state
    __shared__ float wsg[96 * 33];              // 12.7 KB
    __shared__ __align__(16) float Mm[3][25][28];  // 8.4 KB, rows 16B-aligned
    __shared__ unsigned short outb[200 * 32];   // 12.8 KB

    const size_t rowbase = (size_t)n * 1600 + (size_t)tt * 200;

    // ---- init: sp = h chunk 0 (f32), stage step-0 weights ----
    {
        const unsigned short* hrow = hT + rowbase * 128;
        for (int idx = tid; idx < 800; idx += 256) {
            int p = idx >> 2, c8 = (idx & 3) << 3;
            uint4 u = *(const uint4*)(hrow + (size_t)p * 128 + c8);
            float f[8];
            unpk2(u.x, f[0], f[1]); unpk2(u.y, f[2], f[3]);
            unpk2(u.z, f[4], f[5]); unpk2(u.w, f[6], f[7]);
            float* d = sp + p * 36 + c8;
            *(float4*)d       = make_float4(f[0], f[1], f[2], f[3]);
            *(float4*)(d + 4) = make_float4(f[4], f[5], f[6], f[7]);
        }
        for (int idx = tid; idx < 96 * 32; idx += 256)
            wsg[(idx >> 5) * 33 + (idx & 31)] = gw[idx];
        for (int idx = tid; idx < 1875; idx += 256) {
            int k = idx / 625, rem = idx % 625;
            Mm[k][rem / 25][rem % 25] = Aadj[idx] + PA[idx];
        }
    }
    __syncthreads();

    for (int step = 0; step < 4; ++step) {
        // ---- conv 32->96 (round-10 form: scalar LDS reads, broadcast) ----
        float g[3][25];
        {
            const float* gbp = gb + step * 96;
            float b0 = gbp[c], b1 = gbp[32 + c], b2 = gbp[64 + c];
            #pragma unroll
            for (int v = 0; v < 25; ++v) { g[0][v] = b0; g[1][v] = b1; g[2][v] = b2; }
        }
        const float* srow = sp + tl * 25 * 36;
        for (int cin = 0; cin < 32; ++cin) {
            float w0 = wsg[c * 33 + cin];
            float w1 = wsg[(32 + c) * 33 + cin];
            float w2 = wsg[(64 + c) * 33 + cin];
            #pragma unroll
            for (int v = 0; v < 25; ++v) {
                float sv = srow[v * 36 + cin];
                g[0][v] = fmaf(w0, sv, g[0][v]);
                g[1][v] = fmaf(w1, sv, g[1][v]);
                g[2][v] = fmaf(w2, sv, g[2][v]);
            }
        }

        // ---- adjacency mix: Mm rows read as float4 (b128) ----
        float out[25];
        #pragma unroll
        for (int w = 0; w < 25; ++w) out[w] = 0.f;
        #pragma unroll
        for (int k = 0; k < 3; ++k)
            #pragma unroll
            for (int v = 0; v < 25; ++v) {
                float gv = g[k][v];
                const float* mrow = &Mm[k][v][0];
                #pragma unroll
                for (int wc = 0; wc < 6; ++wc) {
                    float4 m4 = *(const float4*)(mrow + wc * 4);
                    out[wc * 4 + 0] = fmaf(gv, m4.x, out[wc * 4 + 0]);
                    out[wc * 4 + 1] = fmaf(gv, m4.y, out[wc * 4 + 1]);
                    out[wc * 4 + 2] = fmaf(gv, m4.z, out[wc * 4 + 2]);
                    out[wc * 4 + 3] = fmaf(gv, m4.w, out[wc * 4 + 3]);
                }
                out[24] = fmaf(gv, mrow[24], out[24]);
            }

        // ---- BN + ReLU ----
        {
            float sc = bsc4[step * 32 + c], sh = bsh4[step * 32 + c];
            #pragma unroll
            for (int w = 0; w < 25; ++w)
                out[w] = fmaxf(fmaf(out[w], sc, sh), 0.f);
        }

        __syncthreads();   // all conv/mix reads of sp, wsg, Mm complete

        // ---- write new sp (f32, next step's input) + bf16 outb ----
        #pragma unroll
        for (int w = 0; w < 25; ++w) {
            sp[(tl * 25 + w) * 36 + c] = out[w];
            outb[(tl * 25 + w) * 32 + c] = bf16of(out[w]);
        }
        __syncthreads();   // sp/outb writes complete

        // ---- store outb -> outsT chunk `step` (coalesced uint4) ----
        {
            unsigned short* orow = outsT + rowbase * 128 + step * 32;
            for (int idx = tid; idx < 800; idx += 256) {
                int p = idx >> 2, c8 = (idx & 3) << 3;
                uint4 u = *(const uint4*)(&outb[p * 32 + c8]);
                *(uint4*)(orow + (size_t)p * 128 + c8) = u;
            }
        }

        if (step < 3) {
            // ---- sp += h chunk step+1 ; stage next weights ----
            const unsigned short* hrow = hT + rowbase * 128 + (step + 1) * 32;
            for (int idx = tid; idx < 800; idx += 256) {
                int p = idx >> 2, c8 = (idx & 3) << 3;
                uint4 u = *(const uint4*)(hrow + (size_t)p * 128 + c8);
                float f[8];
                unpk2(u.x, f[0], f[1]); unpk2(u.y, f[2], f[3]);
                unpk2(u.z, f[4], f[5]); unpk2(u.w, f[6], f[7]);
                float* d = sp + p * 36 + c8;
                #pragma unroll
                for (int q = 0; q < 8; ++q) d[q] += f[q];
            }
            const float* gwp = gw + (step + 1) * 96 * 32;
            for (int idx = tid; idx < 96 * 32; idx += 256)
                wsg[(idx >> 5) * 33 + (idx & 31)] = gwp[idx];
            const float* pap = PA + (step + 1) * 1875;
            for (int idx = tid; idx < 1875; idx += 256) {
                int k = idx / 625, rem = idx % 625;
                Mm[k][rem / 25][rem % 25] = Aadj[idx] + pap[idx];
            }
            __syncthreads();   // sp/wsg/Mm ready for next conv
        }
    }
}

// ---------------------------------------------------------------------------
extern "C" void kernel_launch(void* const* d_in, const int* in_sizes, int n_in,
                              void* d_out, int out_size, void* d_ws, size_t ws_size,
                              hipStream_t stream)
{
    const float* x   = (const float*)d_in[0];
    const float* A   = (const float*)d_in[1];
    const float* rw  = (const float*)d_in[2];
    const float* rwb = (const float*)d_in[3];
    const float* rg  = (const float*)d_in[4];
    const float* rb  = (const float*)d_in[5];
    const float* rm  = (const float*)d_in[6];
    const float* rv  = (const float*)d_in[7];
    const float* gw  = (const float*)d_in[8];
    const float* gb  = (const float*)d_in[9];
    const float* PA  = (const float*)d_in[10];
    const float* bg  = (const float*)d_in[11];
    const float* bb  = (const float*)d_in[12];
    const float* bm  = (const float*)d_in[13];
    const float* bv  = (const float*)d_in[14];
    const float* ew  = (const float*)d_in[15];
    const float* ewb = (const float*)d_in[16];
    const float* eg  = (const float*)d_in[17];
    const float* eb  = (const float*)d_in[18];
    const float* em  = (const float*)d_in[19];
    const float* ev  = (const float*)d_in[20];

    char* wsb = (char*)d_ws;
    unsigned short* hT    = (unsigned short*)wsb;               // 26,214,400 B
    unsigned short* outsT = (unsigned short*)(wsb + 26214400);  // 26,214,400 B
    float*          prm   = (float*)(wsb + 52428800);           // 4 KB

    prep_params<<<1, 256, 0, stream>>>(rwb, rg, rb, rm, rv,
                                       ewb, eg, eb, em, ev,
                                       bg, bb, bm, bv, prm);

    // reduct: x f32 [n][256][1600] -> hT bf16 [n][1600][128]
    gemm_v2<0, 1><<<dim3(25, 1, 64), 256, 0, stream>>>(
        x, rw, prm, prm + 128, nullptr, hT, 256, 128, 1600);

    // fused res2net chain (4 steps, one launch)
    gcn_fused<<<dim3(8, 64), 256, 0, stream>>>(
        hT, outsT, gw, gb, A, PA, prm + 768, prm + 896);

    // expand: outsT bf16 -> d_out f32 [n][256][1600] (+x residual)
    gemm_v2<1, 0><<<dim3(25, 2, 64), 256, 0, stream>>>(
        outsT, ew, prm + 256, prm + 512, x, d_out, 128, 256, 1600);
}